// Round 5
// baseline (491.510 us; speedup 1.0000x reference)
//
#include <hip/hip_runtime.h>
#include <math.h>

#define H2 512
#define NB 64
#define TK 2048
#define SPLIT 16

#define LOG2E 1.44269504088896f
#define TWO_LOG2E 2.88539008177793f

// ---------------- K1: dec_fea = s_t_hat @ W_dp^T + b_dp  [NB, H2] ----------------
__global__ __launch_bounds__(256) void k_decproj(const float* __restrict__ s,
                                                 const float* __restrict__ W,
                                                 const float* __restrict__ bias,
                                                 float* __restrict__ dec) {
    const int bb = blockIdx.x;
    const int wave = threadIdx.x >> 6;
    const int lane = threadIdx.x & 63;
    const float* srow = s + bb * H2;
    float4 s0 = *(const float4*)(srow + lane * 8);
    float4 s1 = *(const float4*)(srow + lane * 8 + 4);
    #pragma unroll
    for (int i = 0; i < 8; ++i) {
        const int n = blockIdx.y * 32 + wave * 8 + i;
        const float* wrow = W + (size_t)n * H2;
        float4 w0 = *(const float4*)(wrow + lane * 8);
        float4 w1 = *(const float4*)(wrow + lane * 8 + 4);
        float acc = s0.x * w0.x + s0.y * w0.y + s0.z * w0.z + s0.w * w0.w +
                    s1.x * w1.x + s1.y * w1.y + s1.z * w1.z + s1.w * w1.w;
        #pragma unroll
        for (int off = 1; off < 64; off <<= 1) acc += __shfl_xor(acc, off, 64);
        if (lane == 0) dec[bb * H2 + n] = acc + bias[n];
    }
}

// ---------------- K2: e[b,t]=exp(score)*mask. 64 rows/block, 2-deep pipelined -----
// grid (TK/64=32, NB), block 256 (4 waves x 16 rows, batches of 4 rows, dbuf'd).
// REP: CSE-proof idempotent repeat — per-rep bijective block swizzle changes load
// addresses each rep (defeats LICM/CSE) while still covering every row with
// identical stores. REP=1 for production.
template <int REP>
__global__ __launch_bounds__(256) void k_scores2(const float* __restrict__ ef,
                                                 const float* __restrict__ cov,
                                                 const float* __restrict__ mask,
                                                 const float* __restrict__ dec,
                                                 const float* __restrict__ wc,
                                                 const float* __restrict__ vw,
                                                 const float* __restrict__ vbp,
                                                 float* __restrict__ w) {
    const int bb = blockIdx.y;
    const int tid = threadIdx.x;
    const int wave = tid >> 6, lane = tid & 63;
    const int n0 = lane * 8;

    __shared__ float pl[64][68];

    float4 d0 = *(const float4*)(dec + bb * H2 + n0);
    float4 d1 = *(const float4*)(dec + bb * H2 + n0 + 4);
    float4 c0 = *(const float4*)(wc + n0);
    float4 c1 = *(const float4*)(wc + n0 + 4);
    float4 v0 = *(const float4*)(vw + n0);
    float4 v1 = *(const float4*)(vw + n0 + 4);

    float vwsum = v0.x + v0.y + v0.z + v0.w + v1.x + v1.y + v1.z + v1.w;
    #pragma unroll
    for (int off = 1; off < 64; off <<= 1) vwsum += __shfl_xor(vwsum, off, 64);

    d0.x *= TWO_LOG2E; d0.y *= TWO_LOG2E; d0.z *= TWO_LOG2E; d0.w *= TWO_LOG2E;
    d1.x *= TWO_LOG2E; d1.y *= TWO_LOG2E; d1.z *= TWO_LOG2E; d1.w *= TWO_LOG2E;
    c0.x *= TWO_LOG2E; c0.y *= TWO_LOG2E; c0.z *= TWO_LOG2E; c0.w *= TWO_LOG2E;
    c1.x *= TWO_LOG2E; c1.y *= TWO_LOG2E; c1.z *= TWO_LOG2E; c1.w *= TWO_LOG2E;
    v0.x *= -2.f; v0.y *= -2.f; v0.z *= -2.f; v0.w *= -2.f;
    v1.x *= -2.f; v1.y *= -2.f; v1.z *= -2.f; v1.w *= -2.f;
    const float vb = vbp[0];

    #pragma unroll 1
    for (int rep = 0; rep < REP; ++rep) {
        const int t0 = ((blockIdx.x + rep * 7) & 31) * 64;   // bijective per rep
        const size_t rowbase = (size_t)bb * TK + t0;

        float4 ea[2][4][2];
        float cv[2][4];
        #pragma unroll
        for (int i = 0; i < 4; ++i) {
            const int r = wave + 4 * i;
            const float* p = ef + (rowbase + r) * H2 + n0;
            ea[0][i][0] = *(const float4*)p;
            ea[0][i][1] = *(const float4*)(p + 4);
            cv[0][i] = cov[rowbase + r];
        }
        #pragma unroll
        for (int j0 = 0; j0 < 16; j0 += 4) {
            const int cur = (j0 >> 2) & 1;
            const int nxt = cur ^ 1;
            if (j0 + 4 < 16) {
                #pragma unroll
                for (int i = 0; i < 4; ++i) {
                    const int r = wave + 4 * (j0 + 4 + i);
                    const float* p = ef + (rowbase + r) * H2 + n0;
                    ea[nxt][i][0] = *(const float4*)p;
                    ea[nxt][i][1] = *(const float4*)(p + 4);
                    cv[nxt][i] = cov[rowbase + r];
                }
            }
            #pragma unroll
            for (int i = 0; i < 4; ++i) {
                const float cvv = cv[cur][i];
                #define TERM(E, D, C, V) \
                    ((V) * __builtin_amdgcn_rcpf(__builtin_amdgcn_exp2f(fmaf((E), TWO_LOG2E, fmaf(cvv, (C), (D)))) + 1.0f))
                const float acc =
                    TERM(ea[cur][i][0].x, d0.x, c0.x, v0.x) + TERM(ea[cur][i][0].y, d0.y, c0.y, v0.y) +
                    TERM(ea[cur][i][0].z, d0.z, c0.z, v0.z) + TERM(ea[cur][i][0].w, d0.w, c0.w, v0.w) +
                    TERM(ea[cur][i][1].x, d1.x, c1.x, v1.x) + TERM(ea[cur][i][1].y, d1.y, c1.y, v1.y) +
                    TERM(ea[cur][i][1].z, d1.z, c1.z, v1.z) + TERM(ea[cur][i][1].w, d1.w, c1.w, v1.w);
                #undef TERM
                pl[wave + 4 * (j0 + i)][lane] = acc;
            }
        }
        __syncthreads();

        const int r = tid >> 2, q = tid & 3;
        const float* prow = &pl[r][q * 16];
        const float4 x0 = *(const float4*)(prow);
        const float4 x1 = *(const float4*)(prow + 4);
        const float4 x2 = *(const float4*)(prow + 8);
        const float4 x3 = *(const float4*)(prow + 12);
        float s = x0.x + x0.y + x0.z + x0.w + x1.x + x1.y + x1.z + x1.w +
                  x2.x + x2.y + x2.z + x2.w + x3.x + x3.y + x3.z + x3.w;
        s += __shfl_xor(s, 1, 64);
        s += __shfl_xor(s, 2, 64);
        if (q == 0) {
            const float score = vwsum + s + vb;
            w[rowbase + r] = __builtin_amdgcn_exp2f(score * LOG2E) * mask[rowbase + r];
        }
        __syncthreads();
    }
}

// ---------------- K4: part[b,sp,:] = sum_t e_t * eo[t,:], 2-deep pipelined --------
// grid (SPLIT, NB), block 256: 128 float4-cols x 2 halves of 64 contiguous rows.
// REP: CSE-proof repeat via per-rep sp swizzle (see K2 comment).
template <int REP>
__global__ __launch_bounds__(256) void k_ctpart(const float* __restrict__ eo,
                                                const float* __restrict__ w,
                                                float* __restrict__ part) {
    const int bb = blockIdx.y;
    const int tid = threadIdx.x;
    const int ng = tid & 127, th = tid >> 7;
    __shared__ float4 red[128];

    #define FMA4(a, r) do { acc.x = fmaf((a), (r).x, acc.x); acc.y = fmaf((a), (r).y, acc.y); \
                            acc.z = fmaf((a), (r).z, acc.z); acc.w = fmaf((a), (r).w, acc.w); } while (0)

    #pragma unroll 1
    for (int rep = 0; rep < REP; ++rep) {
        const int sp = (blockIdx.x + rep * 5) & 15;          // bijective per rep
        const int t0 = sp * 128 + th * 64;
        const float* wp = w + bb * TK + t0;
        const float4* ep = (const float4*)(eo + ((size_t)bb * TK + t0) * H2) + ng;

        float4 acc = make_float4(0.f, 0.f, 0.f, 0.f);
        float4 rr[2][8];
        float4 wv[2][2];
        #pragma unroll
        for (int i = 0; i < 8; ++i) rr[0][i] = ep[(size_t)i * 128];
        wv[0][0] = *(const float4*)(wp);
        wv[0][1] = *(const float4*)(wp + 4);

        #pragma unroll
        for (int c = 0; c < 8; ++c) {
            const int cur = c & 1, nxt = cur ^ 1;
            if (c < 7) {
                const int base = (c + 1) * 8;
                #pragma unroll
                for (int i = 0; i < 8; ++i) rr[nxt][i] = ep[(size_t)(base + i) * 128];
                wv[nxt][0] = *(const float4*)(wp + base);
                wv[nxt][1] = *(const float4*)(wp + base + 4);
            }
            FMA4(wv[cur][0].x, rr[cur][0]);
            FMA4(wv[cur][0].y, rr[cur][1]);
            FMA4(wv[cur][0].z, rr[cur][2]);
            FMA4(wv[cur][0].w, rr[cur][3]);
            FMA4(wv[cur][1].x, rr[cur][4]);
            FMA4(wv[cur][1].y, rr[cur][5]);
            FMA4(wv[cur][1].z, rr[cur][6]);
            FMA4(wv[cur][1].w, rr[cur][7]);
        }

        if (th) red[ng] = acc;
        __syncthreads();
        if (!th) {
            const float4 o = red[ng];
            acc.x += o.x; acc.y += o.y; acc.z += o.z; acc.w += o.w;
            *(float4*)(part + ((size_t)bb * SPLIT + sp) * H2 + ng * 4) = acc;
        }
        __syncthreads();
    }
    #undef FMA4
}

// ---------------- K3: finalize — sum, attn, covnew, ct (one kernel) ---------------
__global__ __launch_bounds__(512) void k_finish(const float* __restrict__ w,
                                                const float* __restrict__ cov,
                                                const float* __restrict__ part,
                                                float* __restrict__ attn,
                                                float* __restrict__ covnew,
                                                float* __restrict__ ct) {
    const int bb = blockIdx.x;
    const int tid = threadIdx.x;
    const int lane = tid & 63, wave = tid >> 6;

    const float4 w4 = *(const float4*)(w + bb * TK + tid * 4);
    float s = w4.x + w4.y + w4.z + w4.w;
    #pragma unroll
    for (int off = 1; off < 64; off <<= 1) s += __shfl_xor(s, off, 64);
    __shared__ float rs[8];
    if (lane == 0) rs[wave] = s;
    __syncthreads();
    s = rs[0] + rs[1] + rs[2] + rs[3] + rs[4] + rs[5] + rs[6] + rs[7];
    const float inv = 1.0f / s;

    const float4 c4 = *(const float4*)(cov + bb * TK + tid * 4);
    float4 a4, n4;
    a4.x = w4.x * inv; a4.y = w4.y * inv; a4.z = w4.z * inv; a4.w = w4.w * inv;
    n4.x = c4.x + a4.x; n4.y = c4.y + a4.y; n4.z = c4.z + a4.z; n4.w = c4.w + a4.w;
    *(float4*)(attn + bb * TK + tid * 4) = a4;
    *(float4*)(covnew + bb * TK + tid * 4) = n4;

    float acc = 0.f;
    #pragma unroll
    for (int sp = 0; sp < SPLIT; ++sp) acc += part[((size_t)bb * SPLIT + sp) * H2 + tid];
    ct[bb * H2 + tid] = acc * inv;
}

extern "C" void kernel_launch(void* const* d_in, const int* in_sizes, int n_in,
                              void* d_out, int out_size, void* d_ws, size_t ws_size,
                              hipStream_t stream) {
    const float* s_t_hat  = (const float*)d_in[0];
    const float* enc_out  = (const float*)d_in[1];
    const float* enc_feat = (const float*)d_in[2];
    const float* mask     = (const float*)d_in[3];
    const float* cov      = (const float*)d_in[4];
    const float* W_dp     = (const float*)d_in[5];
    const float* b_dp     = (const float*)d_in[6];
    const float* W_c      = (const float*)d_in[7];
    const float* v_w      = (const float*)d_in[8];
    const float* v_b      = (const float*)d_in[9];

    float* out = (float*)d_out;
    float* ct     = out;                 // [NB, H2]
    float* attn   = out + NB * H2;       // [NB, TK]
    float* covnew = attn + NB * TK;      // [NB, TK]

    float* dec  = (float*)d_ws;          // [NB, H2]
    float* w    = dec + NB * H2;         // [NB, TK]
    float* part = w + NB * TK;           // [NB, SPLIT, H2]

    k_decproj<<<dim3(NB, 16), 256, 0, stream>>>(s_t_hat, W_dp, b_dp, dec);
    // DIAGNOSTIC (by design, dur inflated ~5x): REP=6 with per-rep address
    // swizzle so loads can't be CSE'd; stores idempotent -> output unchanged.
    k_scores2<6><<<dim3(TK / 64, NB), 256, 0, stream>>>(enc_feat, cov, mask, dec, W_c, v_w, v_b, w);
    k_ctpart<6><<<dim3(SPLIT, NB), 256, 0, stream>>>(enc_out, w, part);
    k_finish<<<NB, 512, 0, stream>>>(w, cov, part, attn, covnew, ct);
}

// Round 6
// 108.972 us; speedup vs baseline: 4.5104x; 4.5104x over previous
//
#include <hip/hip_runtime.h>
#include <math.h>

#define H2 512
#define NB 64
#define TK 2048
#define NTILE 32   // TK/64 tiles per batch row

#define LOG2E 1.44269504088896f
#define TWO_LOG2E 2.88539008177793f

// ---------------- K1: dec_fea = s_t_hat @ W_dp^T + b_dp  [NB, H2] ----------------
__global__ __launch_bounds__(256) void k_decproj(const float* __restrict__ s,
                                                 const float* __restrict__ W,
                                                 const float* __restrict__ bias,
                                                 float* __restrict__ dec) {
    const int bb = blockIdx.x;
    const int wave = threadIdx.x >> 6;
    const int lane = threadIdx.x & 63;
    const float* srow = s + bb * H2;
    float4 s0 = *(const float4*)(srow + lane * 8);
    float4 s1 = *(const float4*)(srow + lane * 8 + 4);
    #pragma unroll
    for (int i = 0; i < 8; ++i) {
        const int n = blockIdx.y * 32 + wave * 8 + i;
        const float* wrow = W + (size_t)n * H2;
        float4 w0 = *(const float4*)(wrow + lane * 8);
        float4 w1 = *(const float4*)(wrow + lane * 8 + 4);
        float acc = s0.x * w0.x + s0.y * w0.y + s0.z * w0.z + s0.w * w0.w +
                    s1.x * w1.x + s1.y * w1.y + s1.z * w1.z + s1.w * w1.w;
        #pragma unroll
        for (int off = 1; off < 64; off <<= 1) acc += __shfl_xor(acc, off, 64);
        if (lane == 0) dec[bb * H2 + n] = acc + bias[n];
    }
}

// ---------------- K2 fused: scores(64 rows) -> e -> ct-partial(same rows) ---------
// grid (NTILE, NB), block 256. Phase A = proven R5 k_scores2 body; Phase B =
// proven R5 k_ctpart body over the block's own 64 rows, weights from LDS.
__global__ __launch_bounds__(256) void k_fused2(const float* __restrict__ ef,
                                                const float* __restrict__ eo,
                                                const float* __restrict__ cov,
                                                const float* __restrict__ mask,
                                                const float* __restrict__ dec,
                                                const float* __restrict__ wc,
                                                const float* __restrict__ vw,
                                                const float* __restrict__ vbp,
                                                float* __restrict__ w,
                                                float* __restrict__ part) {
    const int bb = blockIdx.y;
    const int tile = blockIdx.x;
    const int t0 = tile * 64;
    const int tid = threadIdx.x;
    const int wave = tid >> 6, lane = tid & 63;
    const int n0 = lane * 8;

    __shared__ float pl[64][68];   // Phase-A partials; storage reused as red[] in B
    __shared__ float e_lds[64];
    float4* const red = (float4*)&pl[0][0];

    // ---- Phase A ----
    float4 d0 = *(const float4*)(dec + bb * H2 + n0);
    float4 d1 = *(const float4*)(dec + bb * H2 + n0 + 4);
    float4 c0 = *(const float4*)(wc + n0);
    float4 c1 = *(const float4*)(wc + n0 + 4);
    float4 v0 = *(const float4*)(vw + n0);
    float4 v1 = *(const float4*)(vw + n0 + 4);

    float vwsum = v0.x + v0.y + v0.z + v0.w + v1.x + v1.y + v1.z + v1.w;
    #pragma unroll
    for (int off = 1; off < 64; off <<= 1) vwsum += __shfl_xor(vwsum, off, 64);

    d0.x *= TWO_LOG2E; d0.y *= TWO_LOG2E; d0.z *= TWO_LOG2E; d0.w *= TWO_LOG2E;
    d1.x *= TWO_LOG2E; d1.y *= TWO_LOG2E; d1.z *= TWO_LOG2E; d1.w *= TWO_LOG2E;
    c0.x *= TWO_LOG2E; c0.y *= TWO_LOG2E; c0.z *= TWO_LOG2E; c0.w *= TWO_LOG2E;
    c1.x *= TWO_LOG2E; c1.y *= TWO_LOG2E; c1.z *= TWO_LOG2E; c1.w *= TWO_LOG2E;
    v0.x *= -2.f; v0.y *= -2.f; v0.z *= -2.f; v0.w *= -2.f;
    v1.x *= -2.f; v1.y *= -2.f; v1.z *= -2.f; v1.w *= -2.f;
    const float vb = vbp[0];

    const size_t rowbase = (size_t)bb * TK + t0;

    {
        float4 ea[2][4][2];
        float cv[2][4];
        #pragma unroll
        for (int i = 0; i < 4; ++i) {
            const int r = wave + 4 * i;
            const float* p = ef + (rowbase + r) * H2 + n0;
            ea[0][i][0] = *(const float4*)p;
            ea[0][i][1] = *(const float4*)(p + 4);
            cv[0][i] = cov[rowbase + r];
        }
        #pragma unroll
        for (int j0 = 0; j0 < 16; j0 += 4) {
            const int cur = (j0 >> 2) & 1;
            const int nxt = cur ^ 1;
            if (j0 + 4 < 16) {
                #pragma unroll
                for (int i = 0; i < 4; ++i) {
                    const int r = wave + 4 * (j0 + 4 + i);
                    const float* p = ef + (rowbase + r) * H2 + n0;
                    ea[nxt][i][0] = *(const float4*)p;
                    ea[nxt][i][1] = *(const float4*)(p + 4);
                    cv[nxt][i] = cov[rowbase + r];
                }
            }
            #pragma unroll
            for (int i = 0; i < 4; ++i) {
                const float cvv = cv[cur][i];
                #define TERM(E, D, C, V) \
                    ((V) * __builtin_amdgcn_rcpf(__builtin_amdgcn_exp2f(fmaf((E), TWO_LOG2E, fmaf(cvv, (C), (D)))) + 1.0f))
                const float acc =
                    TERM(ea[cur][i][0].x, d0.x, c0.x, v0.x) + TERM(ea[cur][i][0].y, d0.y, c0.y, v0.y) +
                    TERM(ea[cur][i][0].z, d0.z, c0.z, v0.z) + TERM(ea[cur][i][0].w, d0.w, c0.w, v0.w) +
                    TERM(ea[cur][i][1].x, d1.x, c1.x, v1.x) + TERM(ea[cur][i][1].y, d1.y, c1.y, v1.y) +
                    TERM(ea[cur][i][1].z, d1.z, c1.z, v1.z) + TERM(ea[cur][i][1].w, d1.w, c1.w, v1.w);
                #undef TERM
                pl[wave + 4 * (j0 + i)][lane] = acc;
            }
        }
    }
    __syncthreads();

    {
        const int r = tid >> 2, q = tid & 3;
        const float* prow = &pl[r][q * 16];
        const float4 x0 = *(const float4*)(prow);
        const float4 x1 = *(const float4*)(prow + 4);
        const float4 x2 = *(const float4*)(prow + 8);
        const float4 x3 = *(const float4*)(prow + 12);
        float s = x0.x + x0.y + x0.z + x0.w + x1.x + x1.y + x1.z + x1.w +
                  x2.x + x2.y + x2.z + x2.w + x3.x + x3.y + x3.z + x3.w;
        s += __shfl_xor(s, 1, 64);
        s += __shfl_xor(s, 2, 64);
        if (q == 0) {
            const float score = vwsum + s + vb;
            const float e = __builtin_amdgcn_exp2f(score * LOG2E) * mask[rowbase + r];
            e_lds[r] = e;
            w[rowbase + r] = e;
        }
    }
    __syncthreads();   // pl dead from here; red may reuse its storage

    // ---- Phase B ----
    const int ng = tid & 127, th = tid >> 7;
    const int rb = th * 32;
    const float4* ep = (const float4*)(eo + (rowbase + rb) * H2) + ng;

    #define FMA4(a, r) do { acc.x = fmaf((a), (r).x, acc.x); acc.y = fmaf((a), (r).y, acc.y); \
                            acc.z = fmaf((a), (r).z, acc.z); acc.w = fmaf((a), (r).w, acc.w); } while (0)
    float4 acc = make_float4(0.f, 0.f, 0.f, 0.f);
    float4 rr[2][8];
    float we[2][8];
    #pragma unroll
    for (int i = 0; i < 8; ++i) { rr[0][i] = ep[(size_t)i * 128]; we[0][i] = e_lds[rb + i]; }

    #pragma unroll
    for (int c = 0; c < 4; ++c) {
        const int cur = c & 1, nxt = cur ^ 1;
        if (c < 3) {
            const int base = (c + 1) * 8;
            #pragma unroll
            for (int i = 0; i < 8; ++i) {
                rr[nxt][i] = ep[(size_t)(base + i) * 128];
                we[nxt][i] = e_lds[rb + base + i];
            }
        }
        #pragma unroll
        for (int i = 0; i < 8; ++i) FMA4(we[cur][i], rr[cur][i]);
    }
    #undef FMA4

    if (th) red[ng] = acc;
    __syncthreads();
    if (!th) {
        const float4 o = red[ng];
        acc.x += o.x; acc.y += o.y; acc.z += o.z; acc.w += o.w;
        *(float4*)(part + ((size_t)bb * NTILE + tile) * H2 + ng * 4) = acc;
    }
}

// ---------------- K3: finalize — row sum, attn, covnew, ct ------------------------
__global__ __launch_bounds__(512) void k_finish2(const float* __restrict__ w,
                                                 const float* __restrict__ cov,
                                                 const float* __restrict__ part,
                                                 float* __restrict__ attn,
                                                 float* __restrict__ covnew,
                                                 float* __restrict__ ct) {
    const int bb = blockIdx.x;
    const int tid = threadIdx.x;
    const int lane = tid & 63, wave = tid >> 6;

    const float4 w4 = *(const float4*)(w + bb * TK + tid * 4);
    float s = w4.x + w4.y + w4.z + w4.w;
    #pragma unroll
    for (int off = 1; off < 64; off <<= 1) s += __shfl_xor(s, off, 64);
    __shared__ float rs[8];
    if (lane == 0) rs[wave] = s;
    __syncthreads();
    s = rs[0] + rs[1] + rs[2] + rs[3] + rs[4] + rs[5] + rs[6] + rs[7];
    const float inv = 1.0f / s;

    const float4 c4 = *(const float4*)(cov + bb * TK + tid * 4);
    float4 a4, n4;
    a4.x = w4.x * inv; a4.y = w4.y * inv; a4.z = w4.z * inv; a4.w = w4.w * inv;
    n4.x = c4.x + a4.x; n4.y = c4.y + a4.y; n4.z = c4.z + a4.z; n4.w = c4.w + a4.w;
    *(float4*)(attn + bb * TK + tid * 4) = a4;
    *(float4*)(covnew + bb * TK + tid * 4) = n4;

    float acc = 0.f;
    #pragma unroll
    for (int t = 0; t < NTILE; ++t) acc += part[((size_t)bb * NTILE + t) * H2 + tid];
    ct[bb * H2 + tid] = acc * inv;
}

extern "C" void kernel_launch(void* const* d_in, const int* in_sizes, int n_in,
                              void* d_out, int out_size, void* d_ws, size_t ws_size,
                              hipStream_t stream) {
    const float* s_t_hat  = (const float*)d_in[0];
    const float* enc_out  = (const float*)d_in[1];
    const float* enc_feat = (const float*)d_in[2];
    const float* mask     = (const float*)d_in[3];
    const float* cov      = (const float*)d_in[4];
    const float* W_dp     = (const float*)d_in[5];
    const float* b_dp     = (const float*)d_in[6];
    const float* W_c      = (const float*)d_in[7];
    const float* v_w      = (const float*)d_in[8];
    const float* v_b      = (const float*)d_in[9];

    float* out = (float*)d_out;
    float* ct     = out;                 // [NB, H2]
    float* attn   = out + NB * H2;       // [NB, TK]
    float* covnew = attn + NB * TK;      // [NB, TK]

    float* dec  = (float*)d_ws;          // [NB, H2]            128 KB
    float* w    = dec + NB * H2;         // [NB, TK]            512 KB
    float* part = w + NB * TK;           // [NB, NTILE, H2]     4 MB  (ws >= 8.9 MB, verified R2)

    k_decproj<<<dim3(NB, 16), 256, 0, stream>>>(s_t_hat, W_dp, b_dp, dec);
    k_fused2<<<dim3(NTILE, NB), 256, 0, stream>>>(enc_feat, enc_out, cov, mask, dec,
                                                  W_c, v_w, v_b, w, part);
    k_finish2<<<NB, 512, 0, stream>>>(w, cov, part, attn, covnew, ct);
}